// Round 4
// baseline (189.631 us; speedup 1.0000x reference)
//
#include <hip/hip_runtime.h>
#include <hip/hip_bf16.h>

#define BATCH 64
#define MDIM 512
#define NDIM 1024
#define KDIM 1024

#define BM 256
#define BN 256
#define BK 32
#define NKT (KDIM / BK)     // 32 K-tiles

typedef __attribute__((ext_vector_type(4))) float f32x4;
typedef __attribute__((ext_vector_type(8))) short bf16x8;
typedef __attribute__((ext_vector_type(4))) unsigned int u32x4;

// fp32 pair -> packed bf16x2 (RNE); emits v_cvt_pk_bf16_f32
__device__ __forceinline__ unsigned int cvt2(float lo, float hi) {
    __hip_bfloat162 h = __float22bfloat162_rn(float2{lo, hi});
    return *(unsigned int*)&h;
}

// Phase rhythm (8-phase template, T3+T4+T5): reads/staging issued BEFORE
// barrier#1; own DS ops drained (lgkmcnt 0) after it — this is both the MFMA
// data wait AND the cross-wave release edge for ds_writes (sealed by
// barrier#2). sched_barrier(0) pins motion across each boundary (rule 18).
#define PHASE_PRE  do { __builtin_amdgcn_sched_barrier(0); \
    __builtin_amdgcn_s_barrier(); \
    asm volatile("s_waitcnt lgkmcnt(0)" ::: "memory"); \
    __builtin_amdgcn_sched_barrier(0); \
    __builtin_amdgcn_s_setprio(1); } while (0)
#define PHASE_POST do { __builtin_amdgcn_s_setprio(0); \
    __builtin_amdgcn_sched_barrier(0); \
    __builtin_amdgcn_s_barrier(); \
    __builtin_amdgcn_sched_barrier(0); } while (0)

__global__ __launch_bounds__(512, 2)
void grouped_fc_kernel(const float* __restrict__ X,
                       const float* __restrict__ W,
                       const float* __restrict__ Bias,
                       float* __restrict__ Out) {
    // XCD swizzle (bijective: 512 % 8 == 0): XCD j gets batches [8j, 8j+8)
    const int swz  = (blockIdx.x & 7) * 64 + (blockIdx.x >> 3);
    const int bidx = swz >> 3;     // 0..63 batch
    const int tile = swz & 7;      // 2 M-tiles x 4 N-tiles
    const int tm = tile & 1;
    const int tn = tile >> 1;

    const int tid  = threadIdx.x;
    const int lane = tid & 63;
    const int wid  = tid >> 6;     // 0..7
    const int wm   = wid & 1;      // 2 wave rows (128 out-rows)
    const int wn   = wid >> 1;     // 4 wave cols (64 out-cols)

    // [row][32] bf16 (64 B = 4 x 16B slots); slot s stored at s ^ (row&3).
    // Frag reads: 8-lane groups hit 4 slots x 2 rows = 2-way (free, m136);
    // R3 measured SQ_LDS_BANK_CONFLICT == 0 with this family of swizzle.
    __shared__ unsigned short ldsA[2][BM][BK];
    __shared__ unsigned short ldsB[2][BN][BK];

    const float* srcA = X + ((size_t)bidx * MDIM + (size_t)tm * BM) * KDIM;
    const float* srcB = W + ((size_t)bidx * NDIM + (size_t)tn * BN) * KDIM;

    // staging: thread owns 16 consecutive floats of each 256x32 tile
    const int s_r  = tid >> 1;             // row 0..255
    const int s_cf = (tid & 1) * 16;       // float col offset
    const int sw0  = (((tid & 1) * 2)     ^ (s_r & 3)) * 8;  // swizzled bf16 offs
    const int sw1  = (((tid & 1) * 2 + 1) ^ (s_r & 3)) * 8;

    const int frow = lane & 15;            // row within 16x16 frag
    const int khi  = lane >> 4;            // k-slot 0..3
    const int rsl  = (khi ^ (frow & 3)) * 8;  // swizzled read offs (row&3==frow&3)

    f32x4 sa[4], sb[4];                    // staging regs (1 K-tile in flight)

    auto LOADT = [&](int kt) {
        const float* pa = srcA + (size_t)s_r * KDIM + kt * BK + s_cf;
        const float* pb = srcB + (size_t)s_r * KDIM + kt * BK + s_cf;
#pragma unroll
        for (int v = 0; v < 4; ++v) sa[v] = *(const f32x4*)(pa + v * 4);
#pragma unroll
        for (int v = 0; v < 4; ++v) sb[v] = *(const f32x4*)(pb + v * 4);
    };

    auto WRITET = [&](int buf) {
        u32x4 wa0, wa1, wb0, wb1;
        wa0[0] = cvt2(sa[0][0], sa[0][1]); wa0[1] = cvt2(sa[0][2], sa[0][3]);
        wa0[2] = cvt2(sa[1][0], sa[1][1]); wa0[3] = cvt2(sa[1][2], sa[1][3]);
        wa1[0] = cvt2(sa[2][0], sa[2][1]); wa1[1] = cvt2(sa[2][2], sa[2][3]);
        wa1[2] = cvt2(sa[3][0], sa[3][1]); wa1[3] = cvt2(sa[3][2], sa[3][3]);
        wb0[0] = cvt2(sb[0][0], sb[0][1]); wb0[1] = cvt2(sb[0][2], sb[0][3]);
        wb0[2] = cvt2(sb[1][0], sb[1][1]); wb0[3] = cvt2(sb[1][2], sb[1][3]);
        wb1[0] = cvt2(sb[2][0], sb[2][1]); wb1[1] = cvt2(sb[2][2], sb[2][3]);
        wb1[2] = cvt2(sb[3][0], sb[3][1]); wb1[3] = cvt2(sb[3][2], sb[3][3]);
        *(u32x4*)&ldsA[buf][s_r][sw0] = wa0;
        *(u32x4*)&ldsA[buf][s_r][sw1] = wa1;
        *(u32x4*)&ldsB[buf][s_r][sw0] = wb0;
        *(u32x4*)&ldsB[buf][s_r][sw1] = wb1;
    };

    auto rdA = [&](int buf, int mi) {
        return *(const bf16x8*)&ldsA[buf][wm * 128 + mi * 16 + frow][rsl];
    };
    auto rdB = [&](int buf, int ni) {
        return *(const bf16x8*)&ldsB[buf][wn * 64 + ni * 16 + frow][rsl];
    };

    f32x4 acc[8][4];
#pragma unroll
    for (int mi = 0; mi < 8; ++mi)
#pragma unroll
        for (int ni = 0; ni < 4; ++ni)
            acc[mi][ni] = (f32x4){0.f, 0.f, 0.f, 0.f};

    // prologue: tile 0 -> regs -> LDS buf0; seal before first reads
    LOADT(0);
    WRITET(0);
    asm volatile("s_waitcnt lgkmcnt(0)" ::: "memory");
    __builtin_amdgcn_s_barrier();
    __builtin_amdgcn_sched_barrier(0);

#pragma unroll 1
    for (int kt = 0; kt < NKT; ++kt) {
        const int cur = kt & 1;
        const bool more = (kt + 1 < NKT);
        bf16x8 af[8], b01[2], b23[2];

        // ---- Phase 0: frag reads (A all, B 0-1) + issue next-tile loads ----
#pragma unroll
        for (int mi = 0; mi < 8; ++mi) af[mi] = rdA(cur, mi);
        b01[0] = rdB(cur, 0);
        b01[1] = rdB(cur, 1);
        if (more) LOADT(kt + 1);           // in flight across this MFMA phase
        PHASE_PRE;
#pragma unroll
        for (int mi = 0; mi < 8; ++mi) {
            acc[mi][0] = __builtin_amdgcn_mfma_f32_16x16x32_bf16(af[mi], b01[0], acc[mi][0], 0, 0, 0);
            acc[mi][1] = __builtin_amdgcn_mfma_f32_16x16x32_bf16(af[mi], b01[1], acc[mi][1], 0, 0, 0);
        }
        PHASE_POST;

        // ---- Phase 1: frag reads (B 2-3) + cvt/write next tile -> buf^1 ----
        b23[0] = rdB(cur, 2);
        b23[1] = rdB(cur, 3);
        if (more) WRITET(cur ^ 1);         // vmcnt counted by compiler dep
        PHASE_PRE;                          // lgkm(0) drains writes: release edge
#pragma unroll
        for (int mi = 0; mi < 8; ++mi) {
            acc[mi][2] = __builtin_amdgcn_mfma_f32_16x16x32_bf16(af[mi], b23[0], acc[mi][2], 0, 0, 0);
            acc[mi][3] = __builtin_amdgcn_mfma_f32_16x16x32_bf16(af[mi], b23[1], acc[mi][3], 0, 0, 0);
        }
        PHASE_POST;                         // seals buf^1 for next K-tile
    }

    // epilogue: acc layout col=lane&15, row=(lane>>4)*4+r (m89-verified)
#pragma unroll
    for (int ni = 0; ni < 4; ++ni) {
        const int gc = tn * BN + wn * 64 + ni * 16 + frow;
        const float bv = Bias[bidx * NDIM + gc];
#pragma unroll
        for (int mi = 0; mi < 8; ++mi) {
            const int gr0 = tm * BM + wm * 128 + mi * 16 + (lane >> 4) * 4;
            float* po = Out + ((size_t)bidx * MDIM + gr0) * NDIM + gc;
#pragma unroll
            for (int r = 0; r < 4; ++r)
                po[(size_t)r * NDIM] = acc[mi][ni][r] + bv;
        }
    }
}

extern "C" void kernel_launch(void* const* d_in, const int* in_sizes, int n_in,
                              void* d_out, int out_size, void* d_ws, size_t ws_size,
                              hipStream_t stream) {
    const float* X  = (const float*)d_in[0];
    const float* W  = (const float*)d_in[1];
    const float* Bs = (const float*)d_in[2];
    float* Out = (float*)d_out;

    grouped_fc_kernel<<<dim3(512), dim3(512), 0, stream>>>(X, W, Bs, Out);
}

// Round 6
// 151.545 us; speedup vs baseline: 1.2513x; 1.2513x over previous
//
#include <hip/hip_runtime.h>
#include <hip/hip_bf16.h>

#define BATCH 64
#define MDIM 512
#define NDIM 1024
#define KDIM 1024

#define BM 256
#define BN 256
#define BK 32
#define NKT (KDIM / BK)     // 32 K-tiles

typedef __attribute__((ext_vector_type(4))) float f32x4;
typedef __attribute__((ext_vector_type(8))) short bf16x8;
typedef __attribute__((ext_vector_type(4))) unsigned int u32x4;

// fp32 pair -> packed bf16x2 (RNE); emits v_cvt_pk_bf16_f32
__device__ __forceinline__ unsigned int cvt2(float lo, float hi) {
    __hip_bfloat162 h = __float22bfloat162_rn(float2{lo, hi});
    return *(unsigned int*)&h;
}

// Release-edge barrier: drain OUR ds ops (writes published, reads consumed),
// then raw s_barrier. Deliberately NO vmcnt drain — in-flight global loads
// (next+2 tile) survive the barrier (T4). sched_barrier(0) pins motion
// across the asm/barrier boundary (rule 18).
#define RELEASE_BARRIER do { \
    asm volatile("s_waitcnt lgkmcnt(0)" ::: "memory"); \
    __builtin_amdgcn_sched_barrier(0); \
    __builtin_amdgcn_s_barrier(); \
    __builtin_amdgcn_sched_barrier(0); } while (0)

__global__ __launch_bounds__(512, 2)
void grouped_fc_kernel(const float* __restrict__ X,
                       const float* __restrict__ W,
                       const float* __restrict__ Bias,
                       float* __restrict__ Out) {
    // XCD swizzle (bijective: 512 % 8 == 0): XCD j gets batches [8j, 8j+8),
    // batch-major so a batch's 8 tiles co-reside on one XCD's L2.
    const int swz  = (blockIdx.x & 7) * 64 + (blockIdx.x >> 3);
    const int bidx = swz >> 3;     // 0..63 batch
    const int tile = swz & 7;      // 2 M-tiles x 4 N-tiles
    const int tm = tile & 1;
    const int tn = tile >> 1;

    const int tid  = threadIdx.x;
    const int lane = tid & 63;
    const int wid  = tid >> 6;     // 0..7
    const int wm   = wid & 1;      // 2 wave rows (128 out-rows)
    const int wn   = wid >> 1;     // 4 wave cols (64 out-cols)

    // R3-verified layout (SQ_LDS_BANK_CONFLICT == 0 measured):
    // [row][32] bf16, 4 x 16B slots/row; slot s stored at s ^ ((row>>1)&3).
    __shared__ unsigned short ldsA[2][BM][BK];
    __shared__ unsigned short ldsB[2][BN][BK];

    const float* srcA = X + ((size_t)bidx * MDIM + (size_t)tm * BM) * KDIM;
    const float* srcB = W + ((size_t)bidx * NDIM + (size_t)tn * BN) * KDIM;

    // staging: thread owns slots {tid, tid+512}: row = f>>2, K-slot = f&3
    int s_row[2], s_c[2], s_sw[2];
#pragma unroll
    for (int g = 0; g < 2; ++g) {
        int f = tid + g * 512;
        s_row[g] = f >> 2;
        s_c[g]   = (f & 3) * 8;                           // float col offset
        s_sw[g]  = ((f & 3) ^ ((s_row[g] >> 1) & 3)) * 8; // swizzled elem offset
    }

    // pipeline regs: fp32 in-flight tile (kt+2), bf16 converted tile (kt+1)
    f32x4 fa[2][2], fb[2][2];
    u32x4 ca[2], cb[2];

    auto LOADT = [&](int kt) {                            // issue global loads
#pragma unroll
        for (int g = 0; g < 2; ++g) {
            const float* pa = srcA + (size_t)s_row[g] * KDIM + kt * BK + s_c[g];
            fa[g][0] = *(const f32x4*)(pa);
            fa[g][1] = *(const f32x4*)(pa + 4);
            const float* pb = srcB + (size_t)s_row[g] * KDIM + kt * BK + s_c[g];
            fb[g][0] = *(const f32x4*)(pb);
            fb[g][1] = *(const f32x4*)(pb + 4);
        }
    };

    auto CVTT = [&]() {                                   // fp32 regs -> bf16 regs
#pragma unroll
        for (int g = 0; g < 2; ++g) {
            ca[g][0] = cvt2(fa[g][0][0], fa[g][0][1]);
            ca[g][1] = cvt2(fa[g][0][2], fa[g][0][3]);
            ca[g][2] = cvt2(fa[g][1][0], fa[g][1][1]);
            ca[g][3] = cvt2(fa[g][1][2], fa[g][1][3]);
            cb[g][0] = cvt2(fb[g][0][0], fb[g][0][1]);
            cb[g][1] = cvt2(fb[g][0][2], fb[g][0][3]);
            cb[g][2] = cvt2(fb[g][1][0], fb[g][1][1]);
            cb[g][3] = cvt2(fb[g][1][2], fb[g][1][3]);
        }
    };

    auto WRITET = [&](int buf) {                          // bf16 regs -> LDS
#pragma unroll
        for (int g = 0; g < 2; ++g) {
            *(u32x4*)&ldsA[buf][s_row[g]][s_sw[g]] = ca[g];
            *(u32x4*)&ldsB[buf][s_row[g]][s_sw[g]] = cb[g];
        }
    };

    const int frow = lane & 15;   // frag row; bases 16-aligned so (R>>1)&3 == (frow>>1)&3
    const int rsl  = ((lane >> 4) ^ ((frow >> 1) & 3)) * 8;  // swizzled read offs

    f32x4 acc[8][4];
#pragma unroll
    for (int mi = 0; mi < 8; ++mi)
#pragma unroll
        for (int ni = 0; ni < 4; ++ni)
            acc[mi][ni] = (f32x4){0.f, 0.f, 0.f, 0.f};

    // prologue: fill the 3-deep pipeline
    LOADT(0); CVTT(); WRITET(0);   // tile 0 -> buf0
    LOADT(1); CVTT();              // tile 1 -> bf16 regs
    LOADT(2);                      // tile 2 -> fp32 regs (in flight)

#pragma unroll 2
    for (int kt = 0; kt < NKT; ++kt) {
        const int cur = kt & 1;
        // Seals buf[cur] (writes from last iter drained via lgkm0 before
        // barrier); also guarantees all waves' reads of buf[cur^1] are done.
        RELEASE_BARRIER;

        // publish tile kt+1 into buf^1 — hides under frag reads + MFMA,
        // sealed by next iteration's RELEASE_BARRIER
        if (kt + 1 < NKT) WRITET(cur ^ 1);
        // convert tile kt+2 (vmcnt wait here; loads had a full iteration)
        if (kt + 2 < NKT) CVTT();
        // issue tile kt+3 loads; they fly across the next barrier (no vmcnt drain)
        if (kt + 3 < NKT) LOADT(kt + 3);

        bf16x8 af[8], bfr[4];
#pragma unroll
        for (int mi = 0; mi < 8; ++mi)
            af[mi] = *(const bf16x8*)&ldsA[cur][wm * 128 + mi * 16 + frow][rsl];
#pragma unroll
        for (int ni = 0; ni < 4; ++ni)
            bfr[ni] = *(const bf16x8*)&ldsB[cur][wn * 64 + ni * 16 + frow][rsl];

#pragma unroll
        for (int mi = 0; mi < 8; ++mi)
#pragma unroll
            for (int ni = 0; ni < 4; ++ni)
                acc[mi][ni] = __builtin_amdgcn_mfma_f32_16x16x32_bf16(
                    af[mi], bfr[ni], acc[mi][ni], 0, 0, 0);
    }

    // epilogue: acc layout col=lane&15, row=(lane>>4)*4+r (m89-verified)
#pragma unroll
    for (int ni = 0; ni < 4; ++ni) {
        const int gc = tn * BN + wn * 64 + ni * 16 + frow;
        const float bv = Bias[bidx * NDIM + gc];
#pragma unroll
        for (int mi = 0; mi < 8; ++mi) {
            const int gr0 = tm * BM + wm * 128 + mi * 16 + (lane >> 4) * 4;
            float* po = Out + ((size_t)bidx * MDIM + gr0) * NDIM + gc;
#pragma unroll
            for (int r = 0; r < 4; ++r)
                po[(size_t)r * NDIM] = acc[mi][ni][r] + bv;
        }
    }
}

extern "C" void kernel_launch(void* const* d_in, const int* in_sizes, int n_in,
                              void* d_out, int out_size, void* d_ws, size_t ws_size,
                              hipStream_t stream) {
    const float* X  = (const float*)d_in[0];
    const float* W  = (const float*)d_in[1];
    const float* Bs = (const float*)d_in[2];
    float* Out = (float*)d_out;

    grouped_fc_kernel<<<dim3(512), dim3(512), 0, stream>>>(X, W, Bs, Out);
}

// Round 9
// 142.903 us; speedup vs baseline: 1.3270x; 1.0605x over previous
//
#include <hip/hip_runtime.h>
#include <hip/hip_bf16.h>

#define BATCH 64
#define MDIM 512
#define NDIM 1024
#define KDIM 1024

#define BM 256
#define BN 256
#define BK 64
#define NKT (KDIM / BK)     // 16 K-tiles

typedef __attribute__((ext_vector_type(4))) float f32x4;
typedef __attribute__((ext_vector_type(8))) short bf16x8;
typedef __attribute__((ext_vector_type(4))) unsigned int u32x4;

// fp32 pair -> packed bf16x2 (RNE); emits v_cvt_pk_bf16_f32
__device__ __forceinline__ unsigned int cvt2(float lo, float hi) {
    __hip_bfloat162 h = __float22bfloat162_rn(float2{lo, hi});
    return *(unsigned int*)&h;
}

#define MFMA16(a, b, c) __builtin_amdgcn_mfma_f32_16x16x32_bf16((a), (b), (c), 0, 0, 0)

// 8-phase rhythm (T3+T4+T5): pre-barrier region holds ds_reads + one
// half-tile cvt/ds_write + one half-tile global-load issue. lgkm(0) after
// barrier#1 is BOTH the MFMA data wait and the writer's release edge
// (writes sealed for readers by the K-tile-end barrier). No vmcnt drain
// anywhere in the loop — staging loads stay in flight across barriers;
// cvt's register deps give counted vmcnt(4). sched_barrier(0) pins the
// rhythm (rule 18).
#define PHASE_MID do { __builtin_amdgcn_sched_barrier(0); \
    __builtin_amdgcn_s_barrier(); \
    asm volatile("s_waitcnt lgkmcnt(0)" ::: "memory"); \
    __builtin_amdgcn_sched_barrier(0); \
    __builtin_amdgcn_s_setprio(1); } while (0)
#define PHASE_END do { __builtin_amdgcn_s_setprio(0); \
    __builtin_amdgcn_sched_barrier(0); \
    __builtin_amdgcn_s_barrier(); \
    __builtin_amdgcn_sched_barrier(0); } while (0)

__global__ __launch_bounds__(512, 2)
void grouped_fc_kernel(const float* __restrict__ X,
                       const float* __restrict__ W,
                       const float* __restrict__ Bias,
                       float* __restrict__ Out) {
    // XCD swizzle (bijective: 512 % 8 == 0): XCD j gets batches [8j, 8j+8)
    const int swz  = (blockIdx.x & 7) * 64 + (blockIdx.x >> 3);
    const int bidx = swz >> 3;     // 0..63 batch
    const int tile = swz & 7;      // 2 M-tiles x 4 N-tiles
    const int tm = tile & 1;
    const int tn = tile >> 1;

    const int tid  = threadIdx.x;
    const int lane = tid & 63;
    const int wid  = tid >> 6;     // 0..7
    const int wm   = wid & 1;      // 2 wave rows (128 out-rows)
    const int wn   = wid >> 1;     // 4 wave cols (64 out-cols)

    // [row][64] bf16 = 8 x 16B slots/row; slot s stored at s ^ (row&7).
    // Bank math: both frag reads (16 rows x 4 k-slots) and staging writes
    // (16 rows x 4 slot-pairs) land uniformly 8 lanes per 16B granule —
    // the b128 minimum. 128 KiB total.
    __shared__ unsigned short ldsA[2][BM][BK];
    __shared__ unsigned short ldsB[2][BN][BK];

    const float* srcA = X + ((size_t)bidx * MDIM + (size_t)tm * BM) * KDIM;
    const float* srcB = W + ((size_t)bidx * NDIM + (size_t)tn * BN) * KDIM;

    // staging: 4 threads per row; thread covers 16 fp32 (2 bf16 slots) of a
    // 128-row half-tile
    const int s_r  = tid >> 2;             // 0..127 row within half
    const int s_cf = (tid & 3) * 16;       // fp32 col offset
    const int s_x  = s_r & 7;              // (hv*128)&7 == 0
    const int so0  = (((tid & 3) * 2)     ^ s_x) * 8;  // swizzled elem offs
    const int so1  = (((tid & 3) * 2 + 1) ^ s_x) * 8;

    f32x4 st0[4], st1[4];                  // two ping-pong staging sets

    auto ISSUE = [&](const float* srcbase, int hv, int kt_, f32x4 (&s)[4]) {
        const float* p = srcbase + (size_t)(hv * 128 + s_r) * KDIM + kt_ * BK + s_cf;
#pragma unroll
        for (int v = 0; v < 4; ++v) s[v] = *(const f32x4*)(p + v * 4);
    };

    auto CVTW = [&](unsigned short* ldsbase, int hv, f32x4 (&s)[4]) {
        const int row = hv * 128 + s_r;
        u32x4 w0, w1;
        w0[0] = cvt2(s[0][0], s[0][1]); w0[1] = cvt2(s[0][2], s[0][3]);
        w0[2] = cvt2(s[1][0], s[1][1]); w0[3] = cvt2(s[1][2], s[1][3]);
        w1[0] = cvt2(s[2][0], s[2][1]); w1[1] = cvt2(s[2][2], s[2][3]);
        w1[2] = cvt2(s[3][0], s[3][1]); w1[3] = cvt2(s[3][2], s[3][3]);
        *(u32x4*)&ldsbase[(size_t)row * BK + so0] = w0;
        *(u32x4*)&ldsbase[(size_t)row * BK + so1] = w1;
    };

    // frag read offsets: row&7 == frow&7 (bases are multiples of 8)
    const int frow = lane & 15;
    const int khi  = lane >> 4;            // k sub-slot 0..3
    const int xr   = frow & 7;
    const int oK0  = ((khi)     ^ xr) * 8; // ks=0: slot khi
    const int oK1  = ((4 + khi) ^ xr) * 8; // ks=1: slot 4+khi

    f32x4 acc[8][4];
#pragma unroll
    for (int mi = 0; mi < 8; ++mi)
#pragma unroll
        for (int ni = 0; ni < 4; ++ni)
            acc[mi][ni] = (f32x4){0.f, 0.f, 0.f, 0.f};

    // ---- prologue: stage tile 0 fully; pre-issue tile 1 A-halves ----
    ISSUE(srcA, 0, 0, st0); ISSUE(srcA, 1, 0, st1);
    CVTW(&ldsA[0][0][0], 0, st0); CVTW(&ldsA[0][0][0], 1, st1);
    ISSUE(srcB, 0, 0, st0); ISSUE(srcB, 1, 0, st1);
    CVTW(&ldsB[0][0][0], 0, st0); CVTW(&ldsB[0][0][0], 1, st1);
    ISSUE(srcA, 0, 1, st0); ISSUE(srcA, 1, 1, st1);   // tile1 A-halves in flight
    asm volatile("s_waitcnt lgkmcnt(0)" ::: "memory");
    __builtin_amdgcn_sched_barrier(0);
    __builtin_amdgcn_s_barrier();
    __builtin_amdgcn_sched_barrier(0);

#pragma unroll 1
    for (int kt = 0; kt < NKT; ++kt) {
        const int cur = kt & 1;
        const bool m1 = (kt + 1 < NKT);
        const bool m2 = (kt + 2 < NKT);
        unsigned short* nA = &ldsA[cur ^ 1][0][0];
        unsigned short* nB = &ldsB[cur ^ 1][0][0];
        bf16x8 af[8], bfr[2];

        // ---- Phase 0: ks=0, ni 0-1; write A-h0(kt+1); issue B-h0(kt+1) ----
#pragma unroll
        for (int mi = 0; mi < 8; ++mi)
            af[mi] = *(const bf16x8*)&ldsA[cur][wm * 128 + mi * 16 + frow][oK0];
        bfr[0] = *(const bf16x8*)&ldsB[cur][wn * 64 + 0 * 16 + frow][oK0];
        bfr[1] = *(const bf16x8*)&ldsB[cur][wn * 64 + 1 * 16 + frow][oK0];
        if (m1) { CVTW(nA, 0, st0); ISSUE(srcB, 0, kt + 1, st0); }
        PHASE_MID;
#pragma unroll
        for (int mi = 0; mi < 8; ++mi) {
            acc[mi][0] = MFMA16(af[mi], bfr[0], acc[mi][0]);
            acc[mi][1] = MFMA16(af[mi], bfr[1], acc[mi][1]);
        }
        PHASE_END;

        // ---- Phase 1: ks=0, ni 2-3; write A-h1(kt+1); issue B-h1(kt+1) ----
        bfr[0] = *(const bf16x8*)&ldsB[cur][wn * 64 + 2 * 16 + frow][oK0];
        bfr[1] = *(const bf16x8*)&ldsB[cur][wn * 64 + 3 * 16 + frow][oK0];
        if (m1) { CVTW(nA, 1, st1); ISSUE(srcB, 1, kt + 1, st1); }
        PHASE_MID;
#pragma unroll
        for (int mi = 0; mi < 8; ++mi) {
            acc[mi][2] = MFMA16(af[mi], bfr[0], acc[mi][2]);
            acc[mi][3] = MFMA16(af[mi], bfr[1], acc[mi][3]);
        }
        PHASE_END;

        // ---- Phase 2: ks=1, ni 0-1; write B-h0(kt+1); issue A-h0(kt+2) ----
#pragma unroll
        for (int mi = 0; mi < 8; ++mi)
            af[mi] = *(const bf16x8*)&ldsA[cur][wm * 128 + mi * 16 + frow][oK1];
        bfr[0] = *(const bf16x8*)&ldsB[cur][wn * 64 + 0 * 16 + frow][oK1];
        bfr[1] = *(const bf16x8*)&ldsB[cur][wn * 64 + 1 * 16 + frow][oK1];
        if (m1) CVTW(nB, 0, st0);
        if (m2) ISSUE(srcA, 0, kt + 2, st0);
        PHASE_MID;
#pragma unroll
        for (int mi = 0; mi < 8; ++mi) {
            acc[mi][0] = MFMA16(af[mi], bfr[0], acc[mi][0]);
            acc[mi][1] = MFMA16(af[mi], bfr[1], acc[mi][1]);
        }
        PHASE_END;

        // ---- Phase 3: ks=1, ni 2-3; write B-h1(kt+1); issue A-h1(kt+2) ----
        bfr[0] = *(const bf16x8*)&ldsB[cur][wn * 64 + 2 * 16 + frow][oK1];
        bfr[1] = *(const bf16x8*)&ldsB[cur][wn * 64 + 3 * 16 + frow][oK1];
        if (m1) CVTW(nB, 1, st1);
        if (m2) ISSUE(srcA, 1, kt + 2, st1);
        PHASE_MID;
#pragma unroll
        for (int mi = 0; mi < 8; ++mi) {
            acc[mi][2] = MFMA16(af[mi], bfr[0], acc[mi][2]);
            acc[mi][3] = MFMA16(af[mi], bfr[1], acc[mi][3]);
        }
        PHASE_END;  // seals buf^1 (tile kt+1) for next K-tile's reads
    }

    // epilogue: acc layout col=lane&15, row=(lane>>4)*4+r (m89-verified)
#pragma unroll
    for (int ni = 0; ni < 4; ++ni) {
        const int gc = tn * BN + wn * 64 + ni * 16 + frow;
        const float bv = Bias[bidx * NDIM + gc];
#pragma unroll
        for (int mi = 0; mi < 8; ++mi) {
            const int gr0 = tm * BM + wm * 128 + mi * 16 + (lane >> 4) * 4;
            float* po = Out + ((size_t)bidx * MDIM + gr0) * NDIM + gc;
#pragma unroll
            for (int r = 0; r < 4; ++r)
                po[(size_t)r * NDIM] = acc[mi][ni][r] + bv;
        }
    }
}

extern "C" void kernel_launch(void* const* d_in, const int* in_sizes, int n_in,
                              void* d_out, int out_size, void* d_ws, size_t ws_size,
                              hipStream_t stream) {
    const float* X  = (const float*)d_in[0];
    const float* W  = (const float*)d_in[1];
    const float* Bs = (const float*)d_in[2];
    float* Out = (float*)d_out;

    grouped_fc_kernel<<<dim3(512), dim3(512), 0, stream>>>(X, W, Bs, Out);
}